// Round 12
// baseline (544.517 us; speedup 1.0000x reference)
//
#include <hip/hip_runtime.h>

// ---------------------------------------------------------------------------
// 3-layer GATv2 + classifier on MI355X.
// GEMMs: bf16x3 split-precision MFMA, 2-phase prefetch + XCD swizzle.
// Edge phase (F>=512): FEATURE-SLICED 3-kernel pipeline keeping the gather
// L2-RESIDENT: (A) per-slice partial logits (64-feature slices, slice id
// aligned to dispatch-round-robin XCD so each XCD caches one 2.56 MB slice),
// (B) per-node softmax over slice sums, (C) per-slice weighted aggregation.
// 8-lane-group layout in (A): group=edge, sublane=feature -> 3 shfl / 8 edges.
// F=1024 runs its 16 slices as two sequential 8-slice launches.
// ---------------------------------------------------------------------------

typedef __attribute__((ext_vector_type(8))) short bf16x8;
typedef __attribute__((ext_vector_type(4))) float f32x4;

__device__ __forceinline__ unsigned short bf16rn(float x) {
    union { float f; unsigned int u; } v; v.f = x;
    unsigned int r = v.u + 0x7FFF + ((v.u >> 16) & 1);
    return (unsigned short)(r >> 16);
}
__device__ __forceinline__ float bf16tof(unsigned short h) {
    union { unsigned int u; float f; } v; v.u = ((unsigned int)h) << 16;
    return v.f;
}

typedef __attribute__((address_space(1))) const void* gptr_t;
typedef __attribute__((address_space(3))) void* sptr_t;
__device__ __forceinline__ void gload_lds16(const void* g, void* l) {
    __builtin_amdgcn_global_load_lds((gptr_t)g, (sptr_t)l, 16, 0, 0);
}

// ------------------------- weight split + transpose -------------------------

__global__ __launch_bounds__(256) void splitT_kernel(
    const float* __restrict__ W, unsigned short* __restrict__ Th,
    unsigned short* __restrict__ Tl, int K, int F)
{
    __shared__ float tile[32][33];
    const int tx = threadIdx.x & 31, ty = threadIdx.x >> 5;
    const int k0 = blockIdx.x * 32, f0 = blockIdx.y * 32;
#pragma unroll
    for (int i = 0; i < 32; i += 8)
        tile[ty + i][tx] = W[(size_t)(k0 + ty + i) * F + f0 + tx];
    __syncthreads();
#pragma unroll
    for (int i = 0; i < 32; i += 8) {
        int f = f0 + ty + i, k = k0 + tx;
        float v = tile[tx][ty + i];
        unsigned short h = bf16rn(v);
        Th[(size_t)f * K + k] = h;
        Tl[(size_t)f * K + k] = bf16rn(v - bf16tof(h));
    }
}

__global__ void split_kernel(const float* __restrict__ X,
                             unsigned short* __restrict__ Hi,
                             unsigned short* __restrict__ Lo, int n4)
{
    int i = blockIdx.x * blockDim.x + threadIdx.x;
    if (i >= n4) return;
    float4 v = ((const float4*)X)[i];
    ushort4 h, l;
    h.x = bf16rn(v.x); l.x = bf16rn(v.x - bf16tof(h.x));
    h.y = bf16rn(v.y); l.y = bf16rn(v.y - bf16tof(h.y));
    h.z = bf16rn(v.z); l.z = bf16rn(v.z - bf16tof(h.z));
    h.w = bf16rn(v.w); l.w = bf16rn(v.w - bf16tof(h.w));
    ((ushort4*)Hi)[i] = h;
    ((ushort4*)Lo)[i] = l;
}

// ------------------- bf16x3 MFMA GEMM, fused l/r weights --------------------

template<int BM, int BN>
__global__ __launch_bounds__(256) void gemm_mfma_t(
    const unsigned short* __restrict__ Ahi, const unsigned short* __restrict__ Alo,
    int M, int K,
    const unsigned short* __restrict__ WThA, const unsigned short* __restrict__ WTlA,
    const unsigned short* __restrict__ WThB, const unsigned short* __restrict__ WTlB,
    const float* __restrict__ biasA, const float* __restrict__ biasB,
    float* __restrict__ CA, float* __restrict__ CB, int F, int nby)
{
    constexpr int GA = BM / 16, GB = BN / 16;
    constexpr int NJ = (2 * GA + 2 * GB) / 4;
    constexpr int WM = BM / 2, WN = BN / 2;
    constexpr int MI = WM / 16, NI = WN / 16;
    constexpr int ASZ = BM * 32, BSZ = BN * 32;

    __shared__ unsigned short Ash[2 * ASZ];
    __shared__ unsigned short Asl[2 * ASZ];
    __shared__ unsigned short Bsh[2 * BSZ];
    __shared__ unsigned short Bsl[2 * BSZ];

    const int t = threadIdx.x;
    const int lane = t & 63, wave = t >> 6;

    const int nwg = (int)gridDim.x;
    const int bid = (int)blockIdx.x;
    const int q = nwg >> 3, r = nwg & 7;
    const int xcd = bid & 7, slot = bid >> 3;
    const int gidx = (xcd < r) ? (xcd * (q + 1) + slot)
                               : (r * (q + 1) + (xcd - r) * q + slot);
    const int bx = gidx / nby, byi = gidx % nby;

    const int nyh = nby >> 1;
    const int half = (byi >= nyh) ? 1 : 0;
    const int colBase = (byi - half * nyh) * BN;
    const unsigned short* WTh = half ? WThB : WThA;
    const unsigned short* WTl = half ? WTlB : WTlA;
    const float* bias = half ? biasB : biasA;
    float* C = half ? CB : CA;
    const int rowBase = bx * BM;

    const int wr = wave >> 1, wc = wave & 1;
    const int fr = lane & 15, g = lane >> 4;

    const int srow = lane >> 2;
    const int schunk = ((lane & 3) ^ ((lane >> 3) & 3)) * 8;

    const unsigned short* gsrc[NJ];
    unsigned short* ldst[NJ];
#pragma unroll
    for (int j = 0; j < NJ; ++j) {
        const int grp = wave + 4 * j;
        if (grp < GA) {
            int ga = rowBase + grp * 16 + srow; if (ga > M - 1) ga = M - 1;
            gsrc[j] = Ahi + (size_t)ga * K + schunk;
            ldst[j] = &Ash[grp * 512];
        } else if (grp < 2 * GA) {
            const int r16 = grp - GA;
            int ga = rowBase + r16 * 16 + srow; if (ga > M - 1) ga = M - 1;
            gsrc[j] = Alo + (size_t)ga * K + schunk;
            ldst[j] = &Asl[r16 * 512];
        } else if (grp < 2 * GA + GB) {
            const int r16 = grp - 2 * GA;
            const int gb = colBase + r16 * 16 + srow;
            gsrc[j] = WTh + (size_t)gb * K + schunk;
            ldst[j] = &Bsh[r16 * 512];
        } else {
            const int r16 = grp - 2 * GA - GB;
            const int gb = colBase + r16 * 16 + srow;
            gsrc[j] = WTl + (size_t)gb * K + schunk;
            ldst[j] = &Bsl[r16 * 512];
        }
    }

    auto stage = [&](int dbuf, int koff) {
#pragma unroll
        for (int j = 0; j < NJ; ++j) {
            const int grp = wave + 4 * j;
            const int pl = (grp < 2 * GA) ? ASZ : BSZ;
            gload_lds16(gsrc[j] + koff, ldst[j] + dbuf * pl);
        }
    };

    f32x4 acc[MI][NI];
#pragma unroll
    for (int i = 0; i < MI; ++i)
#pragma unroll
        for (int j = 0; j < NI; ++j) acc[i][j] = (f32x4)(0.f);

    const int fragoff = (fr * 4 + (g ^ ((fr >> 1) & 3))) * 8;

    stage(0, 0);
    __syncthreads();

    const int nt = K >> 5;
    for (int tt = 0; tt < nt; ++tt) {
        const int cur = tt & 1;
        if (tt + 1 < nt) stage(cur ^ 1, (tt + 1) * 32);

        bf16x8 ah[MI], al[MI], bh[NI], bl[NI];
#pragma unroll
        for (int mi = 0; mi < MI; ++mi) {
            ah[mi] = *(const bf16x8*)&Ash[cur * ASZ + (wr * MI + mi) * 512 + fragoff];
            al[mi] = *(const bf16x8*)&Asl[cur * ASZ + (wr * MI + mi) * 512 + fragoff];
        }
#pragma unroll
        for (int ni = 0; ni < NI; ++ni) {
            bh[ni] = *(const bf16x8*)&Bsh[cur * BSZ + (wc * NI + ni) * 512 + fragoff];
            bl[ni] = *(const bf16x8*)&Bsl[cur * BSZ + (wc * NI + ni) * 512 + fragoff];
        }
#pragma unroll
        for (int mi = 0; mi < MI; ++mi)
#pragma unroll
            for (int ni = 0; ni < NI; ++ni) {
                acc[mi][ni] = __builtin_amdgcn_mfma_f32_16x16x32_bf16(ah[mi], bh[ni], acc[mi][ni], 0, 0, 0);
                acc[mi][ni] = __builtin_amdgcn_mfma_f32_16x16x32_bf16(ah[mi], bl[ni], acc[mi][ni], 0, 0, 0);
                acc[mi][ni] = __builtin_amdgcn_mfma_f32_16x16x32_bf16(al[mi], bh[ni], acc[mi][ni], 0, 0, 0);
            }
        __syncthreads();
    }

#pragma unroll
    for (int mi = 0; mi < MI; ++mi) {
        const int row0 = rowBase + wr * WM + mi * 16 + g * 4;
#pragma unroll
        for (int ni = 0; ni < NI; ++ni) {
            const int col = colBase + wc * WN + ni * 16 + fr;
            const float b = bias[col];
#pragma unroll
            for (int rr = 0; rr < 4; ++rr) {
                const int row = row0 + rr;
                if (row < M) C[(size_t)row * F + col] = acc[mi][ni][rr] + b;
            }
        }
    }
}

// --------------------------- f32 classifier GEMM ----------------------------

static constexpr int BMc = 64, BNc = 64, BKc = 16;

__global__ __launch_bounds__(256) void gemm_bias_kernel(
    const float* __restrict__ A, const float* __restrict__ W,
    const float* __restrict__ bias, float* __restrict__ C,
    int M, int K, int F)
{
    __shared__ float As[BKc][BMc];
    __shared__ float Bs[BKc][BNc];
    const int t = threadIdx.x;
    const int bm = blockIdx.x, bn = blockIdx.y;
    const int ty = t >> 4, tx = t & 15;
    const int rowBase = bm * BMc;
    const int colBase = bn * BNc;
    const int aRow = t & 63;
    const int aK = (t >> 6) << 2;
    const int gARow = min(rowBase + aRow, M - 1);
    const int bRow = t >> 4;
    const int bCol = (t & 15) << 2;

    float acc[4][4] = {{0.f, 0.f, 0.f, 0.f}};

    for (int k0 = 0; k0 < K; k0 += BKc) {
        float4 av = *(const float4*)&A[(size_t)gARow * K + k0 + aK];
        float4 bv = *(const float4*)&W[(size_t)(k0 + bRow) * F + colBase + bCol];
        As[aK + 0][aRow] = av.x;
        As[aK + 1][aRow] = av.y;
        As[aK + 2][aRow] = av.z;
        As[aK + 3][aRow] = av.w;
        *(float4*)&Bs[bRow][bCol] = bv;
        __syncthreads();
#pragma unroll
        for (int kk = 0; kk < BKc; ++kk) {
            float4 a4 = *(const float4*)&As[kk][ty << 2];
            float4 b4 = *(const float4*)&Bs[kk][tx << 2];
            float ar[4] = {a4.x, a4.y, a4.z, a4.w};
            float br_[4] = {b4.x, b4.y, b4.z, b4.w};
#pragma unroll
            for (int i = 0; i < 4; ++i)
#pragma unroll
                for (int j = 0; j < 4; ++j)
                    acc[i][j] += ar[i] * br_[j];
        }
        __syncthreads();
    }

    float4 bias4 = *(const float4*)&bias[colBase + (tx << 2)];
    float bb[4] = {bias4.x, bias4.y, bias4.z, bias4.w};
#pragma unroll
    for (int i = 0; i < 4; ++i) {
        int r = rowBase + (ty << 2) + i;
        if (r < M) {
            float4 o;
            o.x = acc[i][0] + bb[0];
            o.y = acc[i][1] + bb[1];
            o.z = acc[i][2] + bb[2];
            o.w = acc[i][3] + bb[3];
            *(float4*)&C[(size_t)r * F + colBase + (tx << 2)] = o;
        }
    }
}

// --------------------------- CSR build kernels ------------------------------

__global__ void zero_ints_kernel(int* __restrict__ p, int n)
{
    int i = blockIdx.x * blockDim.x + threadIdx.x;
    if (i < n) p[i] = 0;
}

__device__ inline void edge_src_dst(const int* __restrict__ ei, int edge,
                                    int E_orig, int& src, int& dst)
{
    if (edge < E_orig) {
        src = ei[edge];
        dst = ei[E_orig + edge];
    } else {
        src = dst = edge - E_orig;   // self-loop
    }
}

__global__ void count_kernel(const int* __restrict__ ei, int E_orig, int E_tot,
                             int* __restrict__ counts)
{
    int e = blockIdx.x * blockDim.x + threadIdx.x;
    if (e >= E_tot) return;
    int src, dst;
    edge_src_dst(ei, e, E_orig, src, dst);
    atomicAdd(&counts[dst], 1);
}

__global__ __launch_bounds__(256) void scan_kernel(const int* __restrict__ counts, int n,
                                                   int* __restrict__ offsets,
                                                   int* __restrict__ cursor)
{
    __shared__ int part[256];
    const int t = threadIdx.x;
    const int chunk = (n + 255) >> 8;
    const int begin = t * chunk;
    const int end = min(begin + chunk, n);
    int s = 0;
    for (int i = begin; i < end; ++i) s += counts[i];
    part[t] = s;
    __syncthreads();
    for (int off = 1; off < 256; off <<= 1) {
        int v = (t >= off) ? part[t - off] : 0;
        __syncthreads();
        part[t] += v;
        __syncthreads();
    }
    int run = (t == 0) ? 0 : part[t - 1];
    for (int i = begin; i < end; ++i) {
        offsets[i] = run;
        cursor[i] = run;
        run += counts[i];
    }
    if (t == 255) offsets[n] = part[255];
}

__global__ void fill_kernel(const int* __restrict__ ei, int E_orig, int E_tot,
                            int* __restrict__ cursor, int* __restrict__ csr_src)
{
    int e = blockIdx.x * blockDim.x + threadIdx.x;
    if (e >= E_tot) return;
    int src, dst;
    edge_src_dst(ei, e, E_orig, src, dst);
    int pos = atomicAdd(&cursor[dst], 1);
    csr_src[pos] = src;
}

// ---------------- sliced edge phase (A): per-slice partial logits -----------
// Block = 4 waves = 4 nodes, slice = s_base + blockIdx%NSL (aligned with the
// round-robin blockIdx->XCD mapping: each XCD's L2 caches one 2.56 MB slice).
// Wave layout: 8 lane-groups of 8; group g = edge i+g, sublane j = feature.
// Cross-feature reduce = 3 shfl per 8 edges.

template<int F, int NS, int NSL>
__global__ __launch_bounds__(256) void slice_logits_kernel(
    const float* __restrict__ xl, const float* __restrict__ xr,
    const float* __restrict__ att, const int* __restrict__ offsets,
    const int* __restrict__ csr_src, float* __restrict__ e_part,
    int N, int s_base)
{
    const int wave = threadIdx.x >> 6, lane = threadIdx.x & 63;
    const int s = s_base + (int)blockIdx.x % NSL;
    const int n = ((int)blockIdx.x / NSL) * 4 + wave;
    if (n >= N) return;
    const int start = offsets[n], end = offsets[n + 1];
    const int g = lane >> 3, j = lane & 7;
    const int f0 = s * 64 + j;

    float xr_r[8], att_r[8];
#pragma unroll
    for (int k = 0; k < 8; ++k) {
        xr_r[k] = __builtin_nontemporal_load(&xr[(size_t)n * F + f0 + 8 * k]);
        att_r[k] = att[f0 + 8 * k];
    }

    for (int i = start; i < end; i += 8) {
        const int src = csr_src[min(i + g, end - 1)];
        const float* row = xl + (size_t)src * F + f0;
        float a = 0.f;
#pragma unroll
        for (int k = 0; k < 8; ++k) {
            float mm = row[8 * k] + xr_r[k];
            mm = fmaxf(mm, 0.2f * mm);       // leaky-relu
            a += mm * att_r[k];
        }
        a += __shfl_xor(a, 1);
        a += __shfl_xor(a, 2);
        a += __shfl_xor(a, 4);
        if (j == 0 && i + g < end)
            __builtin_nontemporal_store(a, &e_part[(size_t)(i + g) * NS + s]);
    }
}

// ---------------- sliced edge phase (B): per-node softmax -------------------

template<int NS>
__global__ __launch_bounds__(256) void edge_softmax_kernel(
    const float* __restrict__ e_part, const int* __restrict__ offsets,
    float* __restrict__ alpha, float* __restrict__ invd, int N)
{
    const int wave = threadIdx.x >> 6, lane = threadIdx.x & 63;
    const int n = blockIdx.x * 4 + wave;
    if (n >= N) return;
    const int start = offsets[n], end = offsets[n + 1];

    float m = -1e30f;
    for (int i = start + lane; i < end; i += 64) {
        float e = 0.f;
#pragma unroll
        for (int sIdx = 0; sIdx < NS; ++sIdx) e += e_part[(size_t)i * NS + sIdx];
        alpha[i] = e;
        m = fmaxf(m, e);
    }
#pragma unroll
    for (int off = 32; off; off >>= 1) m = fmaxf(m, __shfl_xor(m, off));
    float d = 0.f;
    for (int i = start + lane; i < end; i += 64) {
        float w = __expf(alpha[i] - m);
        alpha[i] = w;
        d += w;
    }
#pragma unroll
    for (int off = 32; off; off >>= 1) d += __shfl_xor(d, off);
    if (lane == 0) invd[n] = 1.0f / d;
}

// ---------------- sliced edge phase (C): weighted aggregation ---------------

template<int F, int NS, int NSL, bool SPLIT>
__global__ __launch_bounds__(256) void slice_agg_kernel(
    const float* __restrict__ xl, const float* __restrict__ alpha,
    const float* __restrict__ invd, const int* __restrict__ offsets,
    const int* __restrict__ csr_src, const float* __restrict__ bias,
    float* __restrict__ out_f32, unsigned short* __restrict__ out_hi,
    unsigned short* __restrict__ out_lo, int N, int s_base)
{
    const int wave = threadIdx.x >> 6, lane = threadIdx.x & 63;
    const int s = s_base + (int)blockIdx.x % NSL;
    const int n = ((int)blockIdx.x / NSL) * 4 + wave;
    if (n >= N) return;
    const int start = offsets[n], end = offsets[n + 1];
    const int f0 = s * 64 + lane;

    float acc = 0.f;
    for (int i = start; i < end; i += 8) {
        int srcs[8]; float w[8];
#pragma unroll
        for (int b = 0; b < 8; ++b) {
            const int idx = min(i + b, end - 1);
            srcs[b] = csr_src[idx];
            w[b] = (i + b < end) ? alpha[i + b] : 0.f;
        }
#pragma unroll
        for (int b = 0; b < 8; ++b)
            acc += w[b] * xl[(size_t)srcs[b] * F + f0];
    }

    const float o = fmaxf(acc * invd[n] + bias[f0], 0.f);
    const size_t oidx = (size_t)n * F + f0;
    if constexpr (SPLIT) {
        const unsigned short h = bf16rn(o);
        __builtin_nontemporal_store(h, &out_hi[oidx]);
        __builtin_nontemporal_store(bf16rn(o - bf16tof(h)), &out_lo[oidx]);
    } else {
        __builtin_nontemporal_store(o, &out_f32[oidx]);
    }
}

// ---------------- fused GAT: wave-per-node (F = 128), edge-batched ----------

template<int F, bool SPLIT, int B>
__global__ __launch_bounds__(256) void fused_gat_wave_kernel(
    const float* __restrict__ xl, const float* __restrict__ xr,
    const float* __restrict__ att, const int* __restrict__ offsets,
    const int* __restrict__ csr_src, const float* __restrict__ bias,
    float* __restrict__ out_f32,
    unsigned short* __restrict__ out_hi, unsigned short* __restrict__ out_lo,
    int N)
{
    constexpr int VEC = F / 64;
    constexpr int CW = (VEC >= 4) ? 4 : VEC;
    constexpr int NC = VEC / CW;
    const int wave = threadIdx.x >> 6, lane = threadIdx.x & 63;
    const int n = blockIdx.x * 4 + wave;
    if (n >= N) return;
    const int start = offsets[n], end = offsets[n + 1];

    float xr_r[VEC], att_r[VEC], acc[VEC];
#pragma unroll
    for (int j = 0; j < NC; ++j)
#pragma unroll
        for (int c = 0; c < CW; ++c) {
            const int f = j * 64 * CW + lane * CW + c;
            xr_r[j * CW + c] = xr[(size_t)n * F + f];
            att_r[j * CW + c] = att[f];
            acc[j * CW + c] = 0.f;
        }

    float m = -1e30f, d = 0.f;

    for (int i = start; i < end; i += B) {
        int srcs[B];
#pragma unroll
        for (int b = 0; b < B; ++b) srcs[b] = csr_src[min(i + b, end - 1)];

        float r[B][VEC];
#pragma unroll
        for (int b = 0; b < B; ++b) {
            const float* row = xl + (size_t)srcs[b] * F;
#pragma unroll
            for (int j = 0; j < NC; ++j) {
                if constexpr (CW == 4) {
                    float4 v = *(const float4*)&row[j * 256 + lane * 4];
                    r[b][j * 4 + 0] = v.x; r[b][j * 4 + 1] = v.y;
                    r[b][j * 4 + 2] = v.z; r[b][j * 4 + 3] = v.w;
                } else {
                    float2 v = *(const float2*)&row[lane * 2];
                    r[b][0] = v.x; r[b][1] = v.y;
                }
            }
        }

        float p[B];
#pragma unroll
        for (int b = 0; b < B; ++b) {
            float pp = 0.f;
#pragma unroll
            for (int v = 0; v < VEC; ++v) {
                float mm = r[b][v] + xr_r[v];
                mm = fmaxf(mm, 0.2f * mm);
                pp += mm * att_r[v];
            }
            p[b] = pp;
        }

#pragma unroll
        for (int off = 32; off; off >>= 1)
#pragma unroll
            for (int b = 0; b < B; ++b) p[b] += __shfl_xor(p[b], off);

#pragma unroll
        for (int b = 0; b < B; ++b)
            if (i + b >= end) p[b] = -1e30f;

        float bmax = p[0];
#pragma unroll
        for (int b = 1; b < B; ++b) bmax = fmaxf(bmax, p[b]);
        const float nm = fmaxf(m, bmax);
        const float scale = __expf(m - nm);
        float wg[B], wsumv = 0.f;
#pragma unroll
        for (int b = 0; b < B; ++b) { wg[b] = __expf(p[b] - nm); wsumv += wg[b]; }
        d = d * scale + wsumv;
#pragma unroll
        for (int v = 0; v < VEC; ++v) {
            float a = acc[v] * scale;
#pragma unroll
            for (int b = 0; b < B; ++b) a += wg[b] * r[b][v];
            acc[v] = a;
        }
        m = nm;
    }

    const float inv = 1.0f / d;
#pragma unroll
    for (int j = 0; j < NC; ++j) {
        float o[CW];
#pragma unroll
        for (int c = 0; c < CW; ++c) {
            const int f = j * 64 * CW + lane * CW + c;
            o[c] = fmaxf(acc[j * CW + c] * inv + bias[f], 0.f);
        }
        const size_t base = (size_t)n * F + j * 64 * CW + lane * CW;
        if constexpr (SPLIT) {
            if constexpr (CW == 4) {
                ushort4 h, l;
                h.x = bf16rn(o[0]); l.x = bf16rn(o[0] - bf16tof(h.x));
                h.y = bf16rn(o[1]); l.y = bf16rn(o[1] - bf16tof(h.y));
                h.z = bf16rn(o[2]); l.z = bf16rn(o[2] - bf16tof(h.z));
                h.w = bf16rn(o[3]); l.w = bf16rn(o[3] - bf16tof(h.w));
                *(ushort4*)&out_hi[base] = h;
                *(ushort4*)&out_lo[base] = l;
            } else {
                ushort2 h, l;
                h.x = bf16rn(o[0]); l.x = bf16rn(o[0] - bf16tof(h.x));
                h.y = bf16rn(o[1]); l.y = bf16rn(o[1] - bf16tof(h.y));
                *(ushort2*)&out_hi[base] = h;
                *(ushort2*)&out_lo[base] = l;
            }
        } else {
            if constexpr (CW == 4) {
                float4 v = {o[0], o[1], o[2], o[3]};
                *(float4*)&out_f32[base] = v;
            } else {
                float2 v = {o[0], o[1]};
                *(float2*)&out_f32[base] = v;
            }
        }
    }
}

// ----------------------------------------------------------------------------

extern "C" void kernel_launch(void* const* d_in, const int* in_sizes, int n_in,
                              void* d_out, int out_size, void* d_ws, size_t ws_size,
                              hipStream_t stream)
{
    const float* x   = (const float*)d_in[0];
    const int*   ei  = (const int*)d_in[1];
    const float* Wl1 = (const float*)d_in[2];
    const float* bl1 = (const float*)d_in[3];
    const float* Wr1 = (const float*)d_in[4];
    const float* br1 = (const float*)d_in[5];
    const float* at1 = (const float*)d_in[6];
    const float* b1  = (const float*)d_in[7];
    const float* Wl2 = (const float*)d_in[8];
    const float* bl2 = (const float*)d_in[9];
    const float* Wr2 = (const float*)d_in[10];
    const float* br2 = (const float*)d_in[11];
    const float* at2 = (const float*)d_in[12];
    const float* b2  = (const float*)d_in[13];
    const float* Wl3 = (const float*)d_in[14];
    const float* bl3 = (const float*)d_in[15];
    const float* Wr3 = (const float*)d_in[16];
    const float* br3 = (const float*)d_in[17];
    const float* at3 = (const float*)d_in[18];
    const float* b3  = (const float*)d_in[19];
    const float* Wc  = (const float*)d_in[20];
    const float* bc  = (const float*)d_in[21];

    const int N = in_sizes[0] / 128;       // 10000
    const int E_orig = in_sizes[1] / 2;    // 160000
    const int E_tot = E_orig + N;          // 170000

    size_t off = 0;
    auto alloc = [&](size_t bytes) -> char* {
        char* p = (char*)d_ws + off;
        off += (bytes + 255) & ~(size_t)255;
        return p;
    };
    float* bufA = (float*)alloc((size_t)N * 1024 * 4);          // xl (f32)
    float* bufB = (float*)alloc((size_t)N * 1024 * 4);          // xr (f32), h3 in-place
    unsigned short* S_hi = (unsigned short*)alloc((size_t)N * 1024 * 2);
    unsigned short* S_lo = (unsigned short*)alloc((size_t)N * 1024 * 2);
    unsigned short* WThl = (unsigned short*)alloc((size_t)524288 * 2);
    unsigned short* WTll = (unsigned short*)alloc((size_t)524288 * 2);
    unsigned short* WThr = (unsigned short*)alloc((size_t)524288 * 2);
    unsigned short* WTlr = (unsigned short*)alloc((size_t)524288 * 2);
    float* e_part = (float*)alloc((size_t)E_tot * 16 * 4);
    float* alpha  = (float*)alloc((size_t)E_tot * 4);
    float* invd   = (float*)alloc((size_t)N * 4);
    int* counts  = (int*)alloc((size_t)N * 4);
    int* offsets = (int*)alloc((size_t)(N + 1) * 4);
    int* cursor  = (int*)alloc((size_t)N * 4);
    int* csr_src = (int*)alloc((size_t)E_tot * 4);
    (void)ws_size; (void)n_in; (void)out_size;

    const int eb = (E_tot + 255) / 256;
    const int mb128 = (N + 127) / 128;     // 79
    const int mb64  = (N + 63) / 64;       // 157
    const int nb4 = (N + 3) / 4;           // 4-nodes-per-block grids

    // CSR by dst (edge_index constant across layers)
    zero_ints_kernel<<<(N + 255) / 256, 256, 0, stream>>>(counts, N);
    count_kernel<<<eb, 256, 0, stream>>>(ei, E_orig, E_tot, counts);
    scan_kernel<<<1, 256, 0, stream>>>(counts, N, offsets, cursor);
    fill_kernel<<<eb, 256, 0, stream>>>(ei, E_orig, E_tot, cursor, csr_src);

    // split input x -> S (bf16 hi/lo)
    split_kernel<<<(N * 128 / 4 + 255) / 256, 256, 0, stream>>>(x, S_hi, S_lo, N * 128 / 4);

    // ---- layer 1: 128 -> 1024 ----
    splitT_kernel<<<dim3(128 / 32, 1024 / 32), 256, 0, stream>>>(Wl1, WThl, WTll, 128, 1024);
    splitT_kernel<<<dim3(128 / 32, 1024 / 32), 256, 0, stream>>>(Wr1, WThr, WTlr, 128, 1024);
    gemm_mfma_t<128, 128><<<mb128 * 16, 256, 0, stream>>>(
        S_hi, S_lo, N, 128, WThl, WTll, WThr, WTlr, bl1, br1, bufA, bufB, 1024, 16);
    slice_logits_kernel<1024, 16, 8><<<nb4 * 8, 256, 0, stream>>>(
        bufA, bufB, at1, offsets, csr_src, e_part, N, 0);
    slice_logits_kernel<1024, 16, 8><<<nb4 * 8, 256, 0, stream>>>(
        bufA, bufB, at1, offsets, csr_src, e_part, N, 8);
    edge_softmax_kernel<16><<<nb4, 256, 0, stream>>>(e_part, offsets, alpha, invd, N);
    slice_agg_kernel<1024, 16, 8, true><<<nb4 * 8, 256, 0, stream>>>(
        bufA, alpha, invd, offsets, csr_src, b1, nullptr, S_hi, S_lo, N, 0);
    slice_agg_kernel<1024, 16, 8, true><<<nb4 * 8, 256, 0, stream>>>(
        bufA, alpha, invd, offsets, csr_src, b1, nullptr, S_hi, S_lo, N, 8);

    // ---- layer 2: 1024 -> 512 ----
    splitT_kernel<<<dim3(1024 / 32, 512 / 32), 256, 0, stream>>>(Wl2, WThl, WTll, 1024, 512);
    splitT_kernel<<<dim3(1024 / 32, 512 / 32), 256, 0, stream>>>(Wr2, WThr, WTlr, 1024, 512);
    gemm_mfma_t<128, 128><<<mb128 * 8, 256, 0, stream>>>(
        S_hi, S_lo, N, 1024, WThl, WTll, WThr, WTlr, bl2, br2, bufA, bufB, 512, 8);
    slice_logits_kernel<512, 8, 8><<<nb4 * 8, 256, 0, stream>>>(
        bufA, bufB, at2, offsets, csr_src, e_part, N, 0);
    edge_softmax_kernel<8><<<nb4, 256, 0, stream>>>(e_part, offsets, alpha, invd, N);
    slice_agg_kernel<512, 8, 8, true><<<nb4 * 8, 256, 0, stream>>>(
        bufA, alpha, invd, offsets, csr_src, b2, nullptr, S_hi, S_lo, N, 0);

    // ---- layer 3: 512 -> 128 (table fits L2s; keep fused path) ----
    splitT_kernel<<<dim3(512 / 32, 128 / 32), 256, 0, stream>>>(Wl3, WThl, WTll, 512, 128);
    splitT_kernel<<<dim3(512 / 32, 128 / 32), 256, 0, stream>>>(Wr3, WThr, WTlr, 512, 128);
    gemm_mfma_t<64, 64><<<mb64 * 4, 256, 0, stream>>>(
        S_hi, S_lo, N, 512, WThl, WTll, WThr, WTlr, bl3, br3, bufA, bufB, 128, 4);
    fused_gat_wave_kernel<128, false, 8><<<nb4, 256, 0, stream>>>(
        bufA, bufB, at3, offsets, csr_src, b3, bufB, nullptr, nullptr, N);

    // ---- classifier: 128 -> 64 (f32 vector GEMM) ----
    gemm_bias_kernel<<<dim3((N + BMc - 1) / BMc, 64 / BNc), 256, 0, stream>>>(
        bufB, Wc, bc, (float*)d_out, N, 128, 64);
}

// Round 13
// 394.717 us; speedup vs baseline: 1.3795x; 1.3795x over previous
//
#include <hip/hip_runtime.h>

// ---------------------------------------------------------------------------
// 3-layer GATv2 + classifier on MI355X.  (Round-9 configuration: best known.)
// GEMMs: bf16x3 split-precision MFMA, BMxBNx32 tile, 2-PHASE double-buffered
// global_load_lds prefetch, bijective chunked XCD swizzle (A-panel L2 reuse),
// XOR chunk swizzle (coalesced 64B-line source, 2-way-max LDS bank aliasing).
// Edge phase: wave-per-node online-softmax fused kernel, edge-batched (B rows
// in flight, interleaved shfl-reduce chains, merged softmax update),
// exactly ONE row-gather per edge.
// Activations live as bf16 hi/lo pairs (written by the fused GAT epilogue).
// ---------------------------------------------------------------------------

typedef __attribute__((ext_vector_type(8))) short bf16x8;
typedef __attribute__((ext_vector_type(4))) float f32x4;

__device__ __forceinline__ unsigned short bf16rn(float x) {
    union { float f; unsigned int u; } v; v.f = x;
    unsigned int r = v.u + 0x7FFF + ((v.u >> 16) & 1);
    return (unsigned short)(r >> 16);
}
__device__ __forceinline__ float bf16tof(unsigned short h) {
    union { unsigned int u; float f; } v; v.u = ((unsigned int)h) << 16;
    return v.f;
}

typedef __attribute__((address_space(1))) const void* gptr_t;
typedef __attribute__((address_space(3))) void* sptr_t;
__device__ __forceinline__ void gload_lds16(const void* g, void* l) {
    __builtin_amdgcn_global_load_lds((gptr_t)g, (sptr_t)l, 16, 0, 0);
}

// ------------------------- weight split + transpose -------------------------

__global__ __launch_bounds__(256) void splitT_kernel(
    const float* __restrict__ W, unsigned short* __restrict__ Th,
    unsigned short* __restrict__ Tl, int K, int F)
{
    __shared__ float tile[32][33];
    const int tx = threadIdx.x & 31, ty = threadIdx.x >> 5;
    const int k0 = blockIdx.x * 32, f0 = blockIdx.y * 32;
#pragma unroll
    for (int i = 0; i < 32; i += 8)
        tile[ty + i][tx] = W[(size_t)(k0 + ty + i) * F + f0 + tx];
    __syncthreads();
#pragma unroll
    for (int i = 0; i < 32; i += 8) {
        int f = f0 + ty + i, k = k0 + tx;
        float v = tile[tx][ty + i];
        unsigned short h = bf16rn(v);
        Th[(size_t)f * K + k] = h;
        Tl[(size_t)f * K + k] = bf16rn(v - bf16tof(h));
    }
}

__global__ void split_kernel(const float* __restrict__ X,
                             unsigned short* __restrict__ Hi,
                             unsigned short* __restrict__ Lo, int n4)
{
    int i = blockIdx.x * blockDim.x + threadIdx.x;
    if (i >= n4) return;
    float4 v = ((const float4*)X)[i];
    ushort4 h, l;
    h.x = bf16rn(v.x); l.x = bf16rn(v.x - bf16tof(h.x));
    h.y = bf16rn(v.y); l.y = bf16rn(v.y - bf16tof(h.y));
    h.z = bf16rn(v.z); l.z = bf16rn(v.z - bf16tof(h.z));
    h.w = bf16rn(v.w); l.w = bf16rn(v.w - bf16tof(h.w));
    ((ushort4*)Hi)[i] = h;
    ((ushort4*)Lo)[i] = l;
}

// ------------------- bf16x3 MFMA GEMM, fused l/r weights --------------------

template<int BM, int BN>
__global__ __launch_bounds__(256) void gemm_mfma_t(
    const unsigned short* __restrict__ Ahi, const unsigned short* __restrict__ Alo,
    int M, int K,
    const unsigned short* __restrict__ WThA, const unsigned short* __restrict__ WTlA,
    const unsigned short* __restrict__ WThB, const unsigned short* __restrict__ WTlB,
    const float* __restrict__ biasA, const float* __restrict__ biasB,
    float* __restrict__ CA, float* __restrict__ CB, int F, int nby)
{
    constexpr int GA = BM / 16, GB = BN / 16;
    constexpr int NJ = (2 * GA + 2 * GB) / 4;
    constexpr int WM = BM / 2, WN = BN / 2;
    constexpr int MI = WM / 16, NI = WN / 16;
    constexpr int ASZ = BM * 32, BSZ = BN * 32;

    __shared__ unsigned short Ash[2 * ASZ];
    __shared__ unsigned short Asl[2 * ASZ];
    __shared__ unsigned short Bsh[2 * BSZ];
    __shared__ unsigned short Bsl[2 * BSZ];

    const int t = threadIdx.x;
    const int lane = t & 63, wave = t >> 6;

    const int nwg = (int)gridDim.x;
    const int bid = (int)blockIdx.x;
    const int q = nwg >> 3, r = nwg & 7;
    const int xcd = bid & 7, slot = bid >> 3;
    const int gidx = (xcd < r) ? (xcd * (q + 1) + slot)
                               : (r * (q + 1) + (xcd - r) * q + slot);
    const int bx = gidx / nby, byi = gidx % nby;

    const int nyh = nby >> 1;
    const int half = (byi >= nyh) ? 1 : 0;
    const int colBase = (byi - half * nyh) * BN;
    const unsigned short* WTh = half ? WThB : WThA;
    const unsigned short* WTl = half ? WTlB : WTlA;
    const float* bias = half ? biasB : biasA;
    float* C = half ? CB : CA;
    const int rowBase = bx * BM;

    const int wr = wave >> 1, wc = wave & 1;
    const int fr = lane & 15, g = lane >> 4;

    const int srow = lane >> 2;
    const int schunk = ((lane & 3) ^ ((lane >> 3) & 3)) * 8;

    const unsigned short* gsrc[NJ];
    unsigned short* ldst[NJ];
#pragma unroll
    for (int j = 0; j < NJ; ++j) {
        const int grp = wave + 4 * j;
        if (grp < GA) {
            int ga = rowBase + grp * 16 + srow; if (ga > M - 1) ga = M - 1;
            gsrc[j] = Ahi + (size_t)ga * K + schunk;
            ldst[j] = &Ash[grp * 512];
        } else if (grp < 2 * GA) {
            const int r16 = grp - GA;
            int ga = rowBase + r16 * 16 + srow; if (ga > M - 1) ga = M - 1;
            gsrc[j] = Alo + (size_t)ga * K + schunk;
            ldst[j] = &Asl[r16 * 512];
        } else if (grp < 2 * GA + GB) {
            const int r16 = grp - 2 * GA;
            const int gb = colBase + r16 * 16 + srow;
            gsrc[j] = WTh + (size_t)gb * K + schunk;
            ldst[j] = &Bsh[r16 * 512];
        } else {
            const int r16 = grp - 2 * GA - GB;
            const int gb = colBase + r16 * 16 + srow;
            gsrc[j] = WTl + (size_t)gb * K + schunk;
            ldst[j] = &Bsl[r16 * 512];
        }
    }

    auto stage = [&](int dbuf, int koff) {
#pragma unroll
        for (int j = 0; j < NJ; ++j) {
            const int grp = wave + 4 * j;
            const int pl = (grp < 2 * GA) ? ASZ : BSZ;
            gload_lds16(gsrc[j] + koff, ldst[j] + dbuf * pl);
        }
    };

    f32x4 acc[MI][NI];
#pragma unroll
    for (int i = 0; i < MI; ++i)
#pragma unroll
        for (int j = 0; j < NI; ++j) acc[i][j] = (f32x4)(0.f);

    const int fragoff = (fr * 4 + (g ^ ((fr >> 1) & 3))) * 8;

    stage(0, 0);
    __syncthreads();

    const int nt = K >> 5;
    for (int tt = 0; tt < nt; ++tt) {
        const int cur = tt & 1;
        if (tt + 1 < nt) stage(cur ^ 1, (tt + 1) * 32);

        bf16x8 ah[MI], al[MI], bh[NI], bl[NI];
#pragma unroll
        for (int mi = 0; mi < MI; ++mi) {
            ah[mi] = *(const bf16x8*)&Ash[cur * ASZ + (wr * MI + mi) * 512 + fragoff];
            al[mi] = *(const bf16x8*)&Asl[cur * ASZ + (wr * MI + mi) * 512 + fragoff];
        }
#pragma unroll
        for (int ni = 0; ni < NI; ++ni) {
            bh[ni] = *(const bf16x8*)&Bsh[cur * BSZ + (wc * NI + ni) * 512 + fragoff];
            bl[ni] = *(const bf16x8*)&Bsl[cur * BSZ + (wc * NI + ni) * 512 + fragoff];
        }
#pragma unroll
        for (int mi = 0; mi < MI; ++mi)
#pragma unroll
            for (int ni = 0; ni < NI; ++ni) {
                acc[mi][ni] = __builtin_amdgcn_mfma_f32_16x16x32_bf16(ah[mi], bh[ni], acc[mi][ni], 0, 0, 0);
                acc[mi][ni] = __builtin_amdgcn_mfma_f32_16x16x32_bf16(ah[mi], bl[ni], acc[mi][ni], 0, 0, 0);
                acc[mi][ni] = __builtin_amdgcn_mfma_f32_16x16x32_bf16(al[mi], bh[ni], acc[mi][ni], 0, 0, 0);
            }
        __syncthreads();
    }

#pragma unroll
    for (int mi = 0; mi < MI; ++mi) {
        const int row0 = rowBase + wr * WM + mi * 16 + g * 4;
#pragma unroll
        for (int ni = 0; ni < NI; ++ni) {
            const int col = colBase + wc * WN + ni * 16 + fr;
            const float b = bias[col];
#pragma unroll
            for (int rr = 0; rr < 4; ++rr) {
                const int row = row0 + rr;
                if (row < M) C[(size_t)row * F + col] = acc[mi][ni][rr] + b;
            }
        }
    }
}

// --------------------------- f32 classifier GEMM ----------------------------

static constexpr int BMc = 64, BNc = 64, BKc = 16;

__global__ __launch_bounds__(256) void gemm_bias_kernel(
    const float* __restrict__ A, const float* __restrict__ W,
    const float* __restrict__ bias, float* __restrict__ C,
    int M, int K, int F)
{
    __shared__ float As[BKc][BMc];
    __shared__ float Bs[BKc][BNc];
    const int t = threadIdx.x;
    const int bm = blockIdx.x, bn = blockIdx.y;
    const int ty = t >> 4, tx = t & 15;
    const int rowBase = bm * BMc;
    const int colBase = bn * BNc;
    const int aRow = t & 63;
    const int aK = (t >> 6) << 2;
    const int gARow = min(rowBase + aRow, M - 1);
    const int bRow = t >> 4;
    const int bCol = (t & 15) << 2;

    float acc[4][4] = {{0.f, 0.f, 0.f, 0.f}};

    for (int k0 = 0; k0 < K; k0 += BKc) {
        float4 av = *(const float4*)&A[(size_t)gARow * K + k0 + aK];
        float4 bv = *(const float4*)&W[(size_t)(k0 + bRow) * F + colBase + bCol];
        As[aK + 0][aRow] = av.x;
        As[aK + 1][aRow] = av.y;
        As[aK + 2][aRow] = av.z;
        As[aK + 3][aRow] = av.w;
        *(float4*)&Bs[bRow][bCol] = bv;
        __syncthreads();
#pragma unroll
        for (int kk = 0; kk < BKc; ++kk) {
            float4 a4 = *(const float4*)&As[kk][ty << 2];
            float4 b4 = *(const float4*)&Bs[kk][tx << 2];
            float ar[4] = {a4.x, a4.y, a4.z, a4.w};
            float br_[4] = {b4.x, b4.y, b4.z, b4.w};
#pragma unroll
            for (int i = 0; i < 4; ++i)
#pragma unroll
                for (int j = 0; j < 4; ++j)
                    acc[i][j] += ar[i] * br_[j];
        }
        __syncthreads();
    }

    float4 bias4 = *(const float4*)&bias[colBase + (tx << 2)];
    float bb[4] = {bias4.x, bias4.y, bias4.z, bias4.w};
#pragma unroll
    for (int i = 0; i < 4; ++i) {
        int r = rowBase + (ty << 2) + i;
        if (r < M) {
            float4 o;
            o.x = acc[i][0] + bb[0];
            o.y = acc[i][1] + bb[1];
            o.z = acc[i][2] + bb[2];
            o.w = acc[i][3] + bb[3];
            *(float4*)&C[(size_t)r * F + colBase + (tx << 2)] = o;
        }
    }
}

// --------------------------- CSR build kernels ------------------------------

__global__ void zero_ints_kernel(int* __restrict__ p, int n)
{
    int i = blockIdx.x * blockDim.x + threadIdx.x;
    if (i < n) p[i] = 0;
}

__device__ inline void edge_src_dst(const int* __restrict__ ei, int edge,
                                    int E_orig, int& src, int& dst)
{
    if (edge < E_orig) {
        src = ei[edge];
        dst = ei[E_orig + edge];
    } else {
        src = dst = edge - E_orig;   // self-loop
    }
}

__global__ void count_kernel(const int* __restrict__ ei, int E_orig, int E_tot,
                             int* __restrict__ counts)
{
    int e = blockIdx.x * blockDim.x + threadIdx.x;
    if (e >= E_tot) return;
    int src, dst;
    edge_src_dst(ei, e, E_orig, src, dst);
    atomicAdd(&counts[dst], 1);
}

__global__ __launch_bounds__(256) void scan_kernel(const int* __restrict__ counts, int n,
                                                   int* __restrict__ offsets,
                                                   int* __restrict__ cursor)
{
    __shared__ int part[256];
    const int t = threadIdx.x;
    const int chunk = (n + 255) >> 8;
    const int begin = t * chunk;
    const int end = min(begin + chunk, n);
    int s = 0;
    for (int i = begin; i < end; ++i) s += counts[i];
    part[t] = s;
    __syncthreads();
    for (int off = 1; off < 256; off <<= 1) {
        int v = (t >= off) ? part[t - off] : 0;
        __syncthreads();
        part[t] += v;
        __syncthreads();
    }
    int run = (t == 0) ? 0 : part[t - 1];
    for (int i = begin; i < end; ++i) {
        offsets[i] = run;
        cursor[i] = run;
        run += counts[i];
    }
    if (t == 255) offsets[n] = part[255];
}

__global__ void fill_kernel(const int* __restrict__ ei, int E_orig, int E_tot,
                            int* __restrict__ cursor, int* __restrict__ csr_src)
{
    int e = blockIdx.x * blockDim.x + threadIdx.x;
    if (e >= E_tot) return;
    int src, dst;
    edge_src_dst(ei, e, E_orig, src, dst);
    int pos = atomicAdd(&cursor[dst], 1);
    csr_src[pos] = src;
}

// ---------------- fused GAT: wave-per-node, edge-batched --------------------

template<int F, bool SPLIT, int B>
__global__ __launch_bounds__(256) void fused_gat_wave_kernel(
    const float* __restrict__ xl, const float* __restrict__ xr,
    const float* __restrict__ att, const int* __restrict__ offsets,
    const int* __restrict__ csr_src, const float* __restrict__ bias,
    float* __restrict__ out_f32,
    unsigned short* __restrict__ out_hi, unsigned short* __restrict__ out_lo,
    int N)
{
    constexpr int VEC = F / 64;
    constexpr int CW = (VEC >= 4) ? 4 : VEC;
    constexpr int NC = VEC / CW;
    const int wave = threadIdx.x >> 6, lane = threadIdx.x & 63;
    const int n = blockIdx.x * 4 + wave;
    if (n >= N) return;
    const int start = offsets[n], end = offsets[n + 1];

    float xr_r[VEC], att_r[VEC], acc[VEC];
#pragma unroll
    for (int j = 0; j < NC; ++j)
#pragma unroll
        for (int c = 0; c < CW; ++c) {
            const int f = j * 64 * CW + lane * CW + c;
            xr_r[j * CW + c] = xr[(size_t)n * F + f];
            att_r[j * CW + c] = att[f];
            acc[j * CW + c] = 0.f;
        }

    float m = -1e30f, d = 0.f;

    for (int i = start; i < end; i += B) {
        int srcs[B];
#pragma unroll
        for (int b = 0; b < B; ++b) srcs[b] = csr_src[min(i + b, end - 1)];

        float r[B][VEC];
#pragma unroll
        for (int b = 0; b < B; ++b) {
            const float* row = xl + (size_t)srcs[b] * F;
#pragma unroll
            for (int j = 0; j < NC; ++j) {
                if constexpr (CW == 4) {
                    float4 v = *(const float4*)&row[j * 256 + lane * 4];
                    r[b][j * 4 + 0] = v.x; r[b][j * 4 + 1] = v.y;
                    r[b][j * 4 + 2] = v.z; r[b][j * 4 + 3] = v.w;
                } else {
                    float2 v = *(const float2*)&row[lane * 2];
                    r[b][0] = v.x; r[b][1] = v.y;
                }
            }
        }

        float p[B];
#pragma unroll
        for (int b = 0; b < B; ++b) {
            float pp = 0.f;
#pragma unroll
            for (int v = 0; v < VEC; ++v) {
                float mm = r[b][v] + xr_r[v];
                mm = fmaxf(mm, 0.2f * mm);       // leaky-relu
                pp += mm * att_r[v];
            }
            p[b] = pp;
        }

#pragma unroll
        for (int off = 32; off; off >>= 1)
#pragma unroll
            for (int b = 0; b < B; ++b) p[b] += __shfl_xor(p[b], off);

#pragma unroll
        for (int b = 0; b < B; ++b)
            if (i + b >= end) p[b] = -1e30f;

        float bmax = p[0];
#pragma unroll
        for (int b = 1; b < B; ++b) bmax = fmaxf(bmax, p[b]);
        const float nm = fmaxf(m, bmax);
        const float scale = __expf(m - nm);
        float wg[B], wsumv = 0.f;
#pragma unroll
        for (int b = 0; b < B; ++b) { wg[b] = __expf(p[b] - nm); wsumv += wg[b]; }
        d = d * scale + wsumv;
#pragma unroll
        for (int v = 0; v < VEC; ++v) {
            float a = acc[v] * scale;
#pragma unroll
            for (int b = 0; b < B; ++b) a += wg[b] * r[b][v];
            acc[v] = a;
        }
        m = nm;
    }

    const float inv = 1.0f / d;
#pragma unroll
    for (int j = 0; j < NC; ++j) {
        float o[CW];
#pragma unroll
        for (int c = 0; c < CW; ++c) {
            const int f = j * 64 * CW + lane * CW + c;
            o[c] = fmaxf(acc[j * CW + c] * inv + bias[f], 0.f);
        }
        const size_t base = (size_t)n * F + j * 64 * CW + lane * CW;
        if constexpr (SPLIT) {
            if constexpr (CW == 4) {
                ushort4 h, l;
                h.x = bf16rn(o[0]); l.x = bf16rn(o[0] - bf16tof(h.x));
                h.y = bf16rn(o[1]); l.y = bf16rn(o[1] - bf16tof(h.y));
                h.z = bf16rn(o[2]); l.z = bf16rn(o[2] - bf16tof(h.z));
                h.w = bf16rn(o[3]); l.w = bf16rn(o[3] - bf16tof(h.w));
                *(ushort4*)&out_hi[base] = h;
                *(ushort4*)&out_lo[base] = l;
            } else {
                ushort2 h, l;
                h.x = bf16rn(o[0]); l.x = bf16rn(o[0] - bf16tof(h.x));
                h.y = bf16rn(o[1]); l.y = bf16rn(o[1] - bf16tof(h.y));
                *(ushort2*)&out_hi[base] = h;
                *(ushort2*)&out_lo[base] = l;
            }
        } else {
            if constexpr (CW == 4) {
                float4 v = {o[0], o[1], o[2], o[3]};
                *(float4*)&out_f32[base] = v;
            } else {
                float2 v = {o[0], o[1]};
                *(float2*)&out_f32[base] = v;
            }
        }
    }
}

// ----------------------------------------------------------------------------

extern "C" void kernel_launch(void* const* d_in, const int* in_sizes, int n_in,
                              void* d_out, int out_size, void* d_ws, size_t ws_size,
                              hipStream_t stream)
{
    const float* x   = (const float*)d_in[0];
    const int*   ei  = (const int*)d_in[1];
    const float* Wl1 = (const float*)d_in[2];
    const float* bl1 = (const float*)d_in[3];
    const float* Wr1 = (const float*)d_in[4];
    const float* br1 = (const float*)d_in[5];
    const float* at1 = (const float*)d_in[6];
    const float* b1  = (const float*)d_in[7];
    const float* Wl2 = (const float*)d_in[8];
    const float* bl2 = (const float*)d_in[9];
    const float* Wr2 = (const float*)d_in[10];
    const float* br2 = (const float*)d_in[11];
    const float* at2 = (const float*)d_in[12];
    const float* b2  = (const float*)d_in[13];
    const float* Wl3 = (const float*)d_in[14];
    const float* bl3 = (const float*)d_in[15];
    const float* Wr3 = (const float*)d_in[16];
    const float* br3 = (const float*)d_in[17];
    const float* at3 = (const float*)d_in[18];
    const float* b3  = (const float*)d_in[19];
    const float* Wc  = (const float*)d_in[20];
    const float* bc  = (const float*)d_in[21];

    const int N = in_sizes[0] / 128;       // 10000
    const int E_orig = in_sizes[1] / 2;    // 160000
    const int E_tot = E_orig + N;          // 170000

    size_t off = 0;
    auto alloc = [&](size_t bytes) -> char* {
        char* p = (char*)d_ws + off;
        off += (bytes + 255) & ~(size_t)255;
        return p;
    };
    float* bufA = (float*)alloc((size_t)N * 1024 * 4);          // xl (f32)
    float* bufB = (float*)alloc((size_t)N * 1024 * 4);          // xr (f32), h3 in-place
    unsigned short* S_hi = (unsigned short*)alloc((size_t)N * 1024 * 2);
    unsigned short* S_lo = (unsigned short*)alloc((size_t)N * 1024 * 2);
    unsigned short* WThl = (unsigned short*)alloc((size_t)524288 * 2);
    unsigned short* WTll = (unsigned short*)alloc((size_t)524288 * 2);
    unsigned short* WThr = (unsigned short*)alloc((size_t)524288 * 2);
    unsigned short* WTlr = (unsigned short*)alloc((size_t)524288 * 2);
    int* counts  = (int*)alloc((size_t)N * 4);
    int* offsets = (int*)alloc((size_t)(N + 1) * 4);
    int* cursor  = (int*)alloc((size_t)N * 4);
    int* csr_src = (int*)alloc((size_t)E_tot * 4);
    (void)ws_size; (void)n_in; (void)out_size;

    const int eb = (E_tot + 255) / 256;
    const int mb128 = (N + 127) / 128;     // 79
    const int mb64  = (N + 63) / 64;       // 157
    const int nb4 = (N + 3) / 4;           // wave-per-node blocks

    // CSR by dst (edge_index constant across layers)
    zero_ints_kernel<<<(N + 255) / 256, 256, 0, stream>>>(counts, N);
    count_kernel<<<eb, 256, 0, stream>>>(ei, E_orig, E_tot, counts);
    scan_kernel<<<1, 256, 0, stream>>>(counts, N, offsets, cursor);
    fill_kernel<<<eb, 256, 0, stream>>>(ei, E_orig, E_tot, cursor, csr_src);

    // split input x -> S (bf16 hi/lo)
    split_kernel<<<(N * 128 / 4 + 255) / 256, 256, 0, stream>>>(x, S_hi, S_lo, N * 128 / 4);

    // ---- layer 1: 128 -> 1024 (tile 128x128, 1264 blocks) ----
    splitT_kernel<<<dim3(128 / 32, 1024 / 32), 256, 0, stream>>>(Wl1, WThl, WTll, 128, 1024);
    splitT_kernel<<<dim3(128 / 32, 1024 / 32), 256, 0, stream>>>(Wr1, WThr, WTlr, 128, 1024);
    gemm_mfma_t<128, 128><<<mb128 * 16, 256, 0, stream>>>(
        S_hi, S_lo, N, 128, WThl, WTll, WThr, WTlr, bl1, br1, bufA, bufB, 1024, 16);
    fused_gat_wave_kernel<1024, true, 4><<<nb4, 256, 0, stream>>>(
        bufA, bufB, at1, offsets, csr_src, b1, nullptr, S_hi, S_lo, N);

    // ---- layer 2: 1024 -> 512 (tile 128x128, 632 blocks) ----
    splitT_kernel<<<dim3(1024 / 32, 512 / 32), 256, 0, stream>>>(Wl2, WThl, WTll, 1024, 512);
    splitT_kernel<<<dim3(1024 / 32, 512 / 32), 256, 0, stream>>>(Wr2, WThr, WTlr, 1024, 512);
    gemm_mfma_t<128, 128><<<mb128 * 8, 256, 0, stream>>>(
        S_hi, S_lo, N, 1024, WThl, WTll, WThr, WTlr, bl2, br2, bufA, bufB, 512, 8);
    fused_gat_wave_kernel<512, true, 4><<<nb4, 256, 0, stream>>>(
        bufA, bufB, at2, offsets, csr_src, b2, nullptr, S_hi, S_lo, N);

    // ---- layer 3: 512 -> 128 (tile 64x64, 628 blocks) ----
    splitT_kernel<<<dim3(512 / 32, 128 / 32), 256, 0, stream>>>(Wl3, WThl, WTll, 512, 128);
    splitT_kernel<<<dim3(512 / 32, 128 / 32), 256, 0, stream>>>(Wr3, WThr, WTlr, 512, 128);
    gemm_mfma_t<64, 64><<<mb64 * 4, 256, 0, stream>>>(
        S_hi, S_lo, N, 512, WThl, WTll, WThr, WTlr, bl3, br3, bufA, bufB, 128, 4);
    fused_gat_wave_kernel<128, false, 8><<<nb4, 256, 0, stream>>>(
        bufA, bufB, at3, offsets, csr_src, b3, bufB, nullptr, nullptr, N);

    // ---- classifier: 128 -> 64 (f32 vector GEMM) ----
    gemm_bias_kernel<<<dim3((N + BMc - 1) / BMc, 64 / BNc), 256, 0, stream>>>(
        bufB, Wc, bc, (float*)d_out, N, 128, 64);
}